// Round 11
// baseline (47960.226 us; speedup 1.0000x reference)
//
#include <hip/hip_runtime.h>
#include <hip/hip_fp16.h>
#include <cmath>

#define NN   68     // nodes
#define HALF 36     // k-values per K-split lane
#define NPAD 72     // padded half2-words per buffer (2 chunks of 36)
#define NT   136    // 2 threads per node (K-split), 3 waves

// lane XOR 1 within quad via DPP quad_perm [1,0,3,2] -- pure VALU, no LDS
__device__ __forceinline__ float dpp_xor1(float x) {
    return __int_as_float(
        __builtin_amdgcn_mov_dpp(__float_as_int(x), 0xB1, 0xF, 0xF, true));
}

#if __has_builtin(__builtin_amdgcn_exp2f)
#define FAST_EXP2(x) __builtin_amdgcn_exp2f(x)
#else
#define FAST_EXP2(x) exp2f(x)
#endif
#define FAST_RCP(x) __builtin_amdgcn_rcpf(x)

// Forced-fusion mixed-precision FMA: acc(f32) += c(f32) * f16half(u).
// v_fma_mix_f32 converts the f16 operand to f32 exactly, then does a fused
// f32 FMA -- bit-identical to __half2float + fmaf, in ONE instruction.
// op_sel_hi:[0,1,0] marks src1 as f16; op_sel:[0,1,0] picks its high half.
__device__ __forceinline__ void fmamix_lo(float& acc, float c, unsigned u) {
    asm("v_fma_mix_f32 %0, %1, %2, %3 op_sel_hi:[0,1,0]"
        : "=v"(acc) : "v"(c), "v"(u), "0"(acc));
}
__device__ __forceinline__ void fmamix_hi(float& acc, float c, unsigned u) {
    asm("v_fma_mix_f32 %0, %1, %2, %3 op_sel:[0,1,0] op_sel_hi:[0,1,0]"
        : "=v"(acc) : "v"(c), "v"(u), "0"(acc));
}

__device__ __forceinline__ unsigned packh2(float a, float b) {
    __half2 h = __floats2half2_rn(a, b);   // RNE, no systematic bias
    return *reinterpret_cast<unsigned*>(&h);
}

// one uint4 = 4 packed pairs = k-indices 4i..4i+3 of BOTH E vectors.
// a* accumulate lo halves (E_A -> step T), b* hi halves (E_B -> step T+1).
#define MACH(c, u)                          \
    fmamix_lo(a0, c.x, u.x);                \
    fmamix_hi(b0, c.x, u.x);                \
    fmamix_lo(a1, c.y, u.y);                \
    fmamix_hi(b1, c.y, u.y);                \
    fmamix_lo(a2, c.z, u.z);                \
    fmamix_hi(b2, c.z, u.z);                \
    fmamix_lo(a3, c.w, u.w);                \
    fmamix_hi(b3, c.w, u.w);

// one Euler sub-step (R4-validated fast exp2/rcp math)
#define ELEM(Ein, Iin, CONN, Eout, Iout)                                      \
    {                                                                         \
        const float xE = P1 * (Ein) - P2 * (Iin) + P5 * (CONN) + Pp;          \
        const float Se = FAST_RCP(1.0f + FAST_EXP2(fmaf(kE2, xE, bE2))) - s0E;\
        const float xI = P3 * (Ein) - P4 * (Iin);                             \
        const float Si = FAST_RCP(1.0f + FAST_EXP2(fmaf(kI2, xI, bI2))) - s0I;\
        Eout = fmaf(fmaf(kE - (Ein), Se, -(Ein)), inv_te, (Ein));             \
        Iout = fmaf(fmaf(kI - (Iin), Si, -(Iin)), inv_ti, (Iin));             \
    }

// SUPERSTEP: steps T, T+1, ONE barrier. RBUF holds packed (E_{T-1}, E_T);
// writes packed (E_{T+1}, E_{T+2}) into WBUF. Outputs go to regs D1,D2.
#define SUPER(RBUF, WBUF, D1, D2)                                             \
    {                                                                         \
        const uint4* vp = (const uint4*)&(RBUF)[s * HALF];                    \
        const uint4 u0 = vp[0], u1 = vp[1], u2 = vp[2], u3 = vp[3],           \
                    u4 = vp[4], u5 = vp[5], u6 = vp[6], u7 = vp[7],           \
                    u8 = vp[8];                                               \
        float a0=0.f,a1=0.f,a2=0.f,a3=0.f,b0=0.f,b1=0.f,b2=0.f,b3=0.f;        \
        MACH(q0, u0) MACH(q1, u1) MACH(q2, u2) MACH(q3, u3) MACH(q4, u4)      \
        MACH(q5, u5) MACH(q6, u6) MACH(q7, u7) MACH(q8, u8)                   \
        float pA = (a0 + a1) + (a2 + a3);                                     \
        float pB = (b0 + b1) + (b2 + b3);                                     \
        pA += dpp_xor1(pA);            /* both K-lanes: full dot */           \
        pB += dpp_xor1(pB);                                                   \
        float En1, In1, En2, In2;                                             \
        ELEM(E, I, pA, En1, In1)       /* step T   */                         \
        ELEM(En1, In1, pB, En2, In2)   /* step T+1 */                         \
        (WBUF)[j] = packh2(En1, En2);  /* same-addr same-value x2: free */    \
        D1 = En1 - In1; D2 = En2 - In2;                                       \
        E = En2; I = In2;                                                     \
        asm volatile("s_waitcnt lgkmcnt(0)\ns_barrier" ::: "memory");         \
    }

__global__ __launch_bounds__(NT, 1)
void nmm_kernel(const float* __restrict__ params,
                const float* __restrict__ Cjk,
                const float* __restrict__ y0,
                float* __restrict__ out,
                const int num_steps)
{
#pragma clang fp contract(off)
    const int tid = threadIdx.x;
    const int j   = tid >> 1;    // node 0..67
    const int s   = tid & 1;     // K-half 0/1

    // packed (older E, newer E) f16 pairs, double-buffered
    __shared__ __align__(16) unsigned Pb0[NPAD], Pb1[NPAD];

    const float tau_e = params[0], tau_i = params[1];
    const float P1 = params[2], P2 = params[3], P3 = params[4];
    const float P4 = params[5], P5 = params[6], Pp = params[7];
    const float kE = params[8], kI = params[9];

    const float LOG2E = 1.4426950408889634f;
    const float kE2 = -1.3f * LOG2E, bE2 = (1.3f * 4.0f) * LOG2E;
    const float kI2 = -2.0f * LOG2E, bI2 = (2.0f * 3.7f) * LOG2E;
    const float s0E = 1.0f / (1.0f + expf(5.2f));
    const float s0I = 1.0f / (1.0f + expf(7.4f));
    const float inv_te = 1.0f / tau_e, inv_ti = 1.0f / tau_i;

    // C-row half chunk -> 9 f32 quads (exact); s=1 top quad is zero pad
    const float* crow = Cjk + j * NN + s * HALF;
    const float4 q0 = *(const float4*)(crow +  0);
    const float4 q1 = *(const float4*)(crow +  4);
    const float4 q2 = *(const float4*)(crow +  8);
    const float4 q3 = *(const float4*)(crow + 12);
    const float4 q4 = *(const float4*)(crow + 16);
    const float4 q5 = *(const float4*)(crow + 20);
    const float4 q6 = *(const float4*)(crow + 24);
    const float4 q7 = *(const float4*)(crow + 28);
    const float4 q8 = (s == 0) ? *(const float4*)(crow + 32)
                               : make_float4(0.f, 0.f, 0.f, 0.f);

    // init: reference steps 0 AND 1 both use C@E_0 -> pairs (E0, E0);
    // pads 68..71 zero in both buffers, never written again
    if (tid < NPAD) {
        const float v = (tid < NN) ? y0[tid] : 0.0f;
        Pb0[tid] = packh2(v, v);
        Pb1[tid] = 0u;
    }
    float E = y0[j];
    float I = y0[NN + j];
    asm volatile("s_waitcnt lgkmcnt(0)\ns_barrier" ::: "memory");

    float* op = out + (size_t)j * (size_t)num_steps;

    int t = 0;
    for (; t + 3 < num_steps; t += 4) {
        float d0, d1, d2, d3;
        SUPER(Pb0, Pb1, d0, d1)
        SUPER(Pb1, Pb0, d2, d3)
        if (s == 0) *(float4*)(op + t) = make_float4(d0, d1, d2, d3);
    }
    // generic tails (dead for num_steps % 4 == 0, kept for correctness)
    bool rb1 = false;
    if (t + 1 < num_steps) {
        float d0, d1;
        SUPER(Pb0, Pb1, d0, d1)
        if (s == 0) *(float2*)(op + t) = make_float2(d0, d1);
        t += 2; rb1 = true;
    }
    if (t < num_steps) {   // final odd step: conn = C @ lo-halves (E_{t-1})
        const unsigned* R = rb1 ? Pb1 : Pb0;
        const uint4* vp = (const uint4*)&R[s * HALF];
        const uint4 u0 = vp[0], u1 = vp[1], u2 = vp[2], u3 = vp[3],
                    u4 = vp[4], u5 = vp[5], u6 = vp[6], u7 = vp[7],
                    u8 = vp[8];
        float a0 = 0.f, a1 = 0.f, a2 = 0.f, a3 = 0.f;
#define MACL(c, u)                          \
        fmamix_lo(a0, c.x, u.x);            \
        fmamix_lo(a1, c.y, u.y);            \
        fmamix_lo(a2, c.z, u.z);            \
        fmamix_lo(a3, c.w, u.w);
        MACL(q0, u0) MACL(q1, u1) MACL(q2, u2) MACL(q3, u3) MACL(q4, u4)
        MACL(q5, u5) MACL(q6, u6) MACL(q7, u7) MACL(q8, u8)
#undef MACL
        float pA = (a0 + a1) + (a2 + a3);
        pA += dpp_xor1(pA);
        float En1, In1;
        ELEM(E, I, pA, En1, In1)
        if (s == 0) op[t] = En1 - In1;
    }
}

extern "C" void kernel_launch(void* const* d_in, const int* in_sizes, int n_in,
                              void* d_out, int out_size, void* d_ws, size_t ws_size,
                              hipStream_t stream) {
    const float* params = (const float*)d_in[0];
    const float* Cjk    = (const float*)d_in[1];
    const float* y0     = (const float*)d_in[2];
    const int num_steps = out_size / NN;

    nmm_kernel<<<dim3(1), dim3(NT), 0, stream>>>(
        params, Cjk, y0, (float*)d_out, num_steps);
}

// Round 12
// 32552.789 us; speedup vs baseline: 1.4733x; 1.4733x over previous
//
#include <hip/hip_runtime.h>
#include <hip/hip_fp16.h>
#include <cmath>

#define NN     68    // nodes
#define NT     136   // 2 threads per node (K-split), 3 waves
#define CWORDS 20    // half2 words per K-chunk (18 real + 2 pad)
#define BWORDS 40    // half2 words per E buffer (2 chunks)

typedef _Float16 h2 __attribute__((ext_vector_type(2)));
__device__ __forceinline__ h2 as_h2(unsigned u) {
    return __builtin_bit_cast(h2, u);
}

// lane XOR 1 within quad via DPP quad_perm [1,0,3,2] -- pure VALU, no LDS
__device__ __forceinline__ float dpp_xor1(float x) {
    return __int_as_float(
        __builtin_amdgcn_mov_dpp(__float_as_int(x), 0xB1, 0xF, 0xF, true));
}

#if __has_builtin(__builtin_amdgcn_exp2f)
#define FAST_EXP2(x) __builtin_amdgcn_exp2f(x)
#else
#define FAST_EXP2(x) exp2f(x)
#endif
#define FAST_RCP(x) __builtin_amdgcn_rcpf(x)

// v_dot2_f32_f16 via BUILTIN (round-11 lesson: inline-asm operand
// constraints poison register allocation; builtins keep the allocator free).
// f16 x f16 products are exact in f32; accumulate is f32.
#if __has_builtin(__builtin_amdgcn_fdot2)
#define DOT2(c, e, acc) __builtin_amdgcn_fdot2(as_h2(c), as_h2(e), (acc), false)
#else
__device__ __forceinline__ float dot2_sw(unsigned c, unsigned e, float acc) {
    h2 ch = as_h2(c), eh = as_h2(e);
    acc = fmaf((float)ch.x, (float)eh.x, acc);
    return fmaf((float)ch.y, (float)eh.y, acc);
}
#define DOT2(c, e, acc) dot2_sw(c, e, acc)
#endif

#define DOTA(cq, eq)                 \
    a0 = DOT2(cq.x, eq.x, a0);       \
    a1 = DOT2(cq.y, eq.y, a1);       \
    a2 = DOT2(cq.z, eq.z, a2);       \
    a3 = DOT2(cq.w, eq.w, a3);
#define DOTB(cq, eq)                 \
    b0 = DOT2(cq.x, eq.x, b0);       \
    b1 = DOT2(cq.y, eq.y, b1);       \
    b2 = DOT2(cq.z, eq.z, b2);       \
    b3 = DOT2(cq.w, eq.w, b3);

__device__ __forceinline__ unsigned packh2(float a, float b) {
    __half2 h = __floats2half2_rn(a, b);   // RNE
    return *reinterpret_cast<unsigned*>(&h);
}

// one Euler sub-step (R4-validated fast exp2/rcp math, hand-fma'd)
#define ELEM(Ein, Iin, CONN, Eout, Iout)                                      \
    {                                                                         \
        const float xE = fmaf(P5, (CONN),                                     \
                              fmaf(P1, (Ein), fmaf(-P2, (Iin), Pp)));         \
        const float Se = FAST_RCP(1.0f + FAST_EXP2(fmaf(kE2, xE, bE2))) - s0E;\
        const float xI = fmaf(P3, (Ein), -(P4 * (Iin)));                      \
        const float Si = FAST_RCP(1.0f + FAST_EXP2(fmaf(kI2, xI, bI2))) - s0I;\
        Eout = fmaf(fmaf(kE - (Ein), Se, -(Ein)), inv_te, (Ein));             \
        Iout = fmaf(fmaf(kI - (Iin), Si, -(Iin)), inv_ti, (Iin));             \
    }

// SUPERSTEP: steps T, T+1, ONE barrier. RA/RB hold f16 E_{T-1}/E_T;
// writes f16 E_{T+1}/E_{T+2} into WA/WB. 40 v_dot2 = the whole matvec.
#define SUPER(RA, RB, WA, WB, D1, D2)                                         \
    {                                                                         \
        const uint4* apv = (const uint4*)&(RA)[s * CWORDS];                   \
        const uint4 A0v = apv[0], A1v = apv[1], A2v = apv[2], A3v = apv[3],   \
                    A4v = apv[4];                                             \
        const uint4* bpv = (const uint4*)&(RB)[s * CWORDS];                   \
        const uint4 B0v = bpv[0], B1v = bpv[1], B2v = bpv[2], B3v = bpv[3],   \
                    B4v = bpv[4];                                             \
        float a0=0.f,a1=0.f,a2=0.f,a3=0.f,b0=0.f,b1=0.f,b2=0.f,b3=0.f;        \
        DOTA(c0, A0v) DOTA(c1, A1v) DOTA(c2, A2v) DOTA(c3, A3v) DOTA(c4, A4v) \
        DOTB(c0, B0v) DOTB(c1, B1v) DOTB(c2, B2v) DOTB(c3, B3v) DOTB(c4, B4v) \
        float pA = (a0 + a1) + (a2 + a3);                                     \
        float pB = (b0 + b1) + (b2 + b3);                                     \
        pA += dpp_xor1(pA);            /* both K-lanes: full dot */           \
        pB += dpp_xor1(pB);                                                   \
        float En1, In1, En2, In2;                                             \
        ELEM(E, I, pA, En1, In1)       /* step T   */                         \
        ELEM(En1, In1, pB, En2, In2)   /* step T+1 */                         \
        *(__half*)((char*)(WA) + wboff) = __float2half_rn(En1);               \
        *(__half*)((char*)(WB) + wboff) = __float2half_rn(En2);               \
        D1 = En1 - In1; D2 = En2 - In2;                                       \
        E = En2; I = In2;                                                     \
        asm volatile("s_waitcnt lgkmcnt(0)\ns_barrier" ::: "memory");         \
    }

__global__ __launch_bounds__(NT, 1)
void nmm_kernel(const float* __restrict__ params,
                const float* __restrict__ Cjk,
                const float* __restrict__ y0,
                float* __restrict__ out,
                const int num_steps)
{
#pragma clang fp contract(off)
    const int tid = threadIdx.x;
    const int j   = tid >> 1;    // node 0..67
    const int s   = tid & 1;     // K-half 0/1

    // f16 E buffers: [0]=A0, [1]=B0, [2]=A1, [3]=B1 (two (older,newer) pairs)
    __shared__ __align__(16) unsigned Ebuf[4][BWORDS];

    const float tau_e = params[0], tau_i = params[1];
    const float P1 = params[2], P2 = params[3], P3 = params[4];
    const float P4 = params[5], P5 = params[6], Pp = params[7];
    const float kE = params[8], kI = params[9];

    const float LOG2E = 1.4426950408889634f;
    const float kE2 = -1.3f * LOG2E, bE2 = (1.3f * 4.0f) * LOG2E;
    const float kI2 = -2.0f * LOG2E, bI2 = (2.0f * 3.7f) * LOG2E;
    const float s0E = 1.0f / (1.0f + expf(5.2f));
    const float s0I = 1.0f / (1.0f + expf(7.4f));
    const float inv_te = 1.0f / tau_e, inv_ti = 1.0f / tau_i;

    // C row j, K-chunk s -> 20 half2 words in 5 uint4 regs (20 VGPRs).
    // m<18 guard: words 18,19 of each chunk are pad (the other chunk owns
    // those k); k<NN guard: rows' tail pad. k is always even, k+1 <= 67.
    const float* crow = Cjk + j * NN;
    const int k0 = s * 36;
    auto cp = [&](int m) -> unsigned {
        const int k = k0 + 2 * m;
        return (m < 18 && k < NN) ? packh2(crow[k], crow[k + 1]) : 0u;
    };
    const uint4 c0 = make_uint4(cp(0),  cp(1),  cp(2),  cp(3));
    const uint4 c1 = make_uint4(cp(4),  cp(5),  cp(6),  cp(7));
    const uint4 c2 = make_uint4(cp(8),  cp(9),  cp(10), cp(11));
    const uint4 c3 = make_uint4(cp(12), cp(13), cp(14), cp(15));
    const uint4 c4 = make_uint4(cp(16), cp(17), cp(18), cp(19));

    // init: reference steps 0 AND 1 both use C@E_0 -> pair0 = (E0, E0);
    // pair1 and all pad words zero (never written again)
    for (int idx = tid; idx < 4 * BWORDS; idx += NT) {
        const int b = idx / BWORDS, w = idx % BWORDS;
        unsigned v = 0u;
        if (b < 2) {
            const int si = w / CWORDS, m = w % CWORDS;
            const int k = si * 36 + 2 * m;
            if (m < 18 && k < NN) v = packh2(y0[k], y0[k + 1]);
        }
        Ebuf[b][w] = v;
    }

    // this node's f16 slot: word + byte-half within a buffer
    const int sidx  = (j >= 36) ? 1 : 0;
    const int wj    = sidx * CWORDS + (j - sidx * 36) / 2;
    const int wboff = wj * 4 + (j & 1) * 2;   // byte offset

    float E = y0[j];
    float I = y0[NN + j];
    asm volatile("s_waitcnt lgkmcnt(0)\ns_barrier" ::: "memory");

    float* op = out + (size_t)j * (size_t)num_steps;

    int t = 0;
    for (; t + 3 < num_steps; t += 4) {
        float d0, d1, d2, d3;
        SUPER(Ebuf[0], Ebuf[1], Ebuf[2], Ebuf[3], d0, d1)
        SUPER(Ebuf[2], Ebuf[3], Ebuf[0], Ebuf[1], d2, d3)
        if (s == 0) *(float4*)(op + t) = make_float4(d0, d1, d2, d3);
    }
    // generic tails (dead for num_steps % 4 == 0, kept for correctness)
    bool rb1 = false;
    if (t + 1 < num_steps) {
        float d0, d1;
        SUPER(Ebuf[0], Ebuf[1], Ebuf[2], Ebuf[3], d0, d1)
        if (s == 0) *(float2*)(op + t) = make_float2(d0, d1);
        t += 2; rb1 = true;
    }
    if (t < num_steps) {   // final odd step: conn = C @ E_{t-1} (A buffer)
        const unsigned* RA = rb1 ? Ebuf[2] : Ebuf[0];
        const uint4* apv = (const uint4*)&RA[s * CWORDS];
        const uint4 A0v = apv[0], A1v = apv[1], A2v = apv[2], A3v = apv[3],
                    A4v = apv[4];
        float a0 = 0.f, a1 = 0.f, a2 = 0.f, a3 = 0.f;
        DOTA(c0, A0v) DOTA(c1, A1v) DOTA(c2, A2v) DOTA(c3, A3v) DOTA(c4, A4v)
        float pA = (a0 + a1) + (a2 + a3);
        pA += dpp_xor1(pA);
        float En1, In1;
        ELEM(E, I, pA, En1, In1)
        if (s == 0) op[t] = En1 - In1;
    }
}

extern "C" void kernel_launch(void* const* d_in, const int* in_sizes, int n_in,
                              void* d_out, int out_size, void* d_ws, size_t ws_size,
                              hipStream_t stream) {
    const float* params = (const float*)d_in[0];
    const float* Cjk    = (const float*)d_in[1];
    const float* y0     = (const float*)d_in[2];
    const int num_steps = out_size / NN;

    nmm_kernel<<<dim3(1), dim3(NT), 0, stream>>>(
        params, Cjk, y0, (float*)d_out, num_steps);
}

// Round 13
// 30397.046 us; speedup vs baseline: 1.5778x; 1.0709x over previous
//
#include <hip/hip_runtime.h>
#include <hip/hip_fp16.h>
#include <cmath>

#define NN 68     // nodes
#define NT 136    // 2 threads per node (K-split), 3 waves
#define BW 72     // words per buffer: 2 chunks x 18 pairs x 2 (A,B interleaved)

typedef _Float16 h2 __attribute__((ext_vector_type(2)));
__device__ __forceinline__ h2 as_h2(unsigned u) {
    return __builtin_bit_cast(h2, u);
}

// lane XOR 1 within quad via DPP quad_perm [1,0,3,2] -- pure VALU, no LDS
__device__ __forceinline__ float dpp_xor1(float x) {
    return __int_as_float(
        __builtin_amdgcn_mov_dpp(__float_as_int(x), 0xB1, 0xF, 0xF, true));
}

#if __has_builtin(__builtin_amdgcn_exp2f)
#define FAST_EXP2(x) __builtin_amdgcn_exp2f(x)
#else
#define FAST_EXP2(x) exp2f(x)
#endif
#define FAST_RCP(x) __builtin_amdgcn_rcpf(x)

#if __has_builtin(__builtin_amdgcn_fdot2)
#define DOT2(c, e, acc) __builtin_amdgcn_fdot2(as_h2(c), as_h2(e), (acc), false)
#else
__device__ __forceinline__ float dot2_sw(unsigned c, unsigned e, float acc) {
    h2 ch = as_h2(c), eh = as_h2(e);
    acc = fmaf((float)ch.x, (float)eh.x, acc);
    return fmaf((float)ch.y, (float)eh.y, acc);
}
#define DOT2(c, e, acc) dot2_sw(c, e, acc)
#endif

__device__ __forceinline__ unsigned packh2(float a, float b) {
    __half2 h = __floats2half2_rn(a, b);   // RNE
    return *reinterpret_cast<unsigned*>(&h);
}

// Interleaved layout: word 2p = A-pair(k=2p), word 2p+1 = B-pair(k=2p).
// uint4 uq = (A_2q, B_2q, A_2q+1, B_2q+1). One c-quad covers pairs 4g..4g+3.
#define MAC8(c, uA, uB)                          \
    a0 = DOT2(c.x, uA.x, a0); b0 = DOT2(c.x, uA.y, b0); \
    a1 = DOT2(c.y, uA.z, a1); b1 = DOT2(c.y, uA.w, b1); \
    a2 = DOT2(c.z, uB.x, a2); b2 = DOT2(c.z, uB.y, b2); \
    a3 = DOT2(c.w, uB.z, a3); b3 = DOT2(c.w, uB.w, b3);

// one Euler sub-step (R4-validated fast exp2/rcp math, hand-fma'd)
#define ELEM(Ein, Iin, CONN, Eout, Iout)                                      \
    {                                                                         \
        const float xE = fmaf(P5, (CONN),                                     \
                              fmaf(P1, (Ein), fmaf(-P2, (Iin), Pp)));         \
        const float Se = FAST_RCP(1.0f + FAST_EXP2(fmaf(kE2, xE, bE2))) - s0E;\
        const float xI = fmaf(P3, (Ein), -(P4 * (Iin)));                      \
        const float Si = FAST_RCP(1.0f + FAST_EXP2(fmaf(kI2, xI, bI2))) - s0I;\
        Eout = fmaf(fmaf(kE - (Ein), Se, -(Ein)), inv_te, (Ein));             \
        Iout = fmaf(fmaf(kI - (Iin), Si, -(Iin)), inv_ti, (Iin));             \
    }

// SUPERSTEP: steps T, T+1, ONE barrier, NO pre-barrier waitcnt (round-13
// gamble: reads are issued post-release, chip-time after all writes were
// issued; early En1 write further ages the writes). 9 ds_read_b128,
// 36 v_dot2 -- bitwise-identical trajectory to R12 absent races.
#define SUPER(R, W, D1, D2)                                                   \
    {                                                                         \
        const uint4* vp_ = (const uint4*)&(R)[s * 36];                        \
        const uint4 u0 = vp_[0], u1 = vp_[1], u2 = vp_[2], u3 = vp_[3],       \
                    u4 = vp_[4], u5 = vp_[5], u6 = vp_[6], u7 = vp_[7],       \
                    u8 = vp_[8];                                              \
        float a0=0.f,a1=0.f,a2=0.f,a3=0.f,b0=0.f,b1=0.f,b2=0.f,b3=0.f;        \
        MAC8(c0, u0, u1) MAC8(c1, u2, u3)                                     \
        MAC8(c2, u4, u5) MAC8(c3, u6, u7)                                     \
        a0 = DOT2(c4x, u8.x, a0); b0 = DOT2(c4x, u8.y, b0);                   \
        a1 = DOT2(c4y, u8.z, a1); b1 = DOT2(c4y, u8.w, b1);                   \
        float pA = (a0 + a1) + (a2 + a3);                                     \
        float pB = (b0 + b1) + (b2 + b3);                                     \
        pA += dpp_xor1(pA);            /* both K-lanes: full dot */           \
        pB += dpp_xor1(pB);                                                   \
        float En1, In1, En2, In2;                                             \
        ELEM(E, I, pA, En1, In1)       /* step T */                           \
        *(__half*)((char*)(W) + wbA) = __float2half_rn(En1);  /* early */     \
        ELEM(En1, In1, pB, En2, In2)   /* step T+1 */                         \
        *(__half*)((char*)(W) + wbB) = __float2half_rn(En2);                  \
        D1 = En1 - In1; D2 = En2 - In2;                                       \
        E = En2; I = In2;                                                     \
        asm volatile("s_barrier" ::: "memory");                               \
    }

__global__ __launch_bounds__(NT, 1)
void nmm_kernel(const float* __restrict__ params,
                const float* __restrict__ Cjk,
                const float* __restrict__ y0,
                float* __restrict__ out,
                const int num_steps)
{
#pragma clang fp contract(off)
    const int tid = threadIdx.x;
    const int j   = tid >> 1;    // node 0..67
    const int s   = tid & 1;     // K-half 0/1

    // interleaved f16 (A,B) buffers, ping-ponged per superstep
    __shared__ __align__(16) unsigned Pb0[BW], Pb1[BW];

    const float tau_e = params[0], tau_i = params[1];
    const float P1 = params[2], P2 = params[3], P3 = params[4];
    const float P4 = params[5], P5 = params[6], Pp = params[7];
    const float kE = params[8], kI = params[9];

    const float LOG2E = 1.4426950408889634f;
    const float kE2 = -1.3f * LOG2E, bE2 = (1.3f * 4.0f) * LOG2E;
    const float kI2 = -2.0f * LOG2E, bI2 = (2.0f * 3.7f) * LOG2E;
    const float s0E = 1.0f / (1.0f + expf(5.2f));
    const float s0I = 1.0f / (1.0f + expf(7.4f));
    const float inv_te = 1.0f / tau_e, inv_ti = 1.0f / tau_i;

    // C row j, K-chunk s -> 18 half2 words (s=1: pairs 16,17 are zero pad)
    const float* crow = Cjk + j * NN;
    const int k0 = s * 36;
    auto cp = [&](int m) -> unsigned {
        const int k = k0 + 2 * m;
        return (k + 1 < NN) ? packh2(crow[k], crow[k + 1]) : 0u;
    };
    const uint4 c0 = make_uint4(cp(0),  cp(1),  cp(2),  cp(3));
    const uint4 c1 = make_uint4(cp(4),  cp(5),  cp(6),  cp(7));
    const uint4 c2 = make_uint4(cp(8),  cp(9),  cp(10), cp(11));
    const uint4 c3 = make_uint4(cp(12), cp(13), cp(14), cp(15));
    const unsigned c4x = cp(16), c4y = cp(17);

    // init: reference steps 0 AND 1 both use C@E_0 -> A = B = E_0 pairs
    for (int idx = tid; idx < 2 * BW; idx += NT) {
        const int b  = (idx >= BW) ? 1 : 0;
        const int w  = idx - b * BW;
        const int si = w / 36, wl = w - si * 36, pl = wl >> 1;
        const int k  = si * 36 + 2 * pl;
        unsigned v = 0u;
        if (b == 0 && k + 1 < NN) v = packh2(y0[k], y0[k + 1]);
        (b ? Pb1 : Pb0)[w] = v;
    }

    // this node's write slots (byte offsets): A-word then B-word
    const int siW = (j >= 36) ? 1 : 0;
    const int kl  = j - siW * 36;
    const int wbA = (siW * 36 + 2 * (kl >> 1)) * 4 + (kl & 1) * 2;
    const int wbB = wbA + 4;

    float E = y0[j];
    float I = y0[NN + j];
    // init barrier keeps the full waitcnt (one-time cost)
    asm volatile("s_waitcnt lgkmcnt(0)\ns_barrier" ::: "memory");

    float* op = out + (size_t)j * (size_t)num_steps;

    int t = 0;
    for (; t + 3 < num_steps; t += 4) {
        float d0, d1, d2, d3;
        SUPER(Pb0, Pb1, d0, d1)
        SUPER(Pb1, Pb0, d2, d3)
        if (s == 0) *(float4*)(op + t) = make_float4(d0, d1, d2, d3);
    }
    // generic tails (dead for num_steps % 4 == 0, kept for correctness)
    bool rb1 = false;
    if (t + 1 < num_steps) {
        float d0, d1;
        SUPER(Pb0, Pb1, d0, d1)
        if (s == 0) *(float2*)(op + t) = make_float2(d0, d1);
        t += 2; rb1 = true;
    }
    if (t < num_steps) {   // final odd step: conn = C @ A-halves (E_{t-1})
        const unsigned* R = rb1 ? Pb1 : Pb0;
        const uint4* vp_ = (const uint4*)&R[s * 36];
        const uint4 u0 = vp_[0], u1 = vp_[1], u2 = vp_[2], u3 = vp_[3],
                    u4 = vp_[4], u5 = vp_[5], u6 = vp_[6], u7 = vp_[7],
                    u8 = vp_[8];
        float a0 = 0.f, a1 = 0.f, a2 = 0.f, a3 = 0.f;
#define MACL(c, uA, uB)                     \
        a0 = DOT2(c.x, uA.x, a0);           \
        a1 = DOT2(c.y, uA.z, a1);           \
        a2 = DOT2(c.z, uB.x, a2);           \
        a3 = DOT2(c.w, uB.z, a3);
        MACL(c0, u0, u1) MACL(c1, u2, u3) MACL(c2, u4, u5) MACL(c3, u6, u7)
        a0 = DOT2(c4x, u8.x, a0);
        a1 = DOT2(c4y, u8.z, a1);
#undef MACL
        float pA = (a0 + a1) + (a2 + a3);
        pA += dpp_xor1(pA);
        float En1, In1;
        ELEM(E, I, pA, En1, In1)
        if (s == 0) op[t] = En1 - In1;
    }
}

extern "C" void kernel_launch(void* const* d_in, const int* in_sizes, int n_in,
                              void* d_out, int out_size, void* d_ws, size_t ws_size,
                              hipStream_t stream) {
    const float* params = (const float*)d_in[0];
    const float* Cjk    = (const float*)d_in[1];
    const float* y0     = (const float*)d_in[2];
    const int num_steps = out_size / NN;

    nmm_kernel<<<dim3(1), dim3(NT), 0, stream>>>(
        params, Cjk, y0, (float*)d_out, num_steps);
}